// Round 1
// baseline (1665.092 us; speedup 1.0000x reference)
//
#include <hip/hip_runtime.h>
#include <math.h>

#define NN 100000
#define NE 1600000
#define D 128

// ---------------------------------------------------------------------------
// GEMM: h[r][o] = sum_k x[r][k] * W[o][k]   (h = x @ W^T)
// Thread-per-row. x row lives in 128 VGPRs (static indexing via full unroll).
// W indices are wave-uniform -> compiler emits s_load; inner loop is pure
// v_fma with one SGPR operand. 4 accumulators break the dependent FMA chain.
// ---------------------------------------------------------------------------
__global__ __launch_bounds__(256) void gemm_kernel(const float* __restrict__ x,
                                                   const float* __restrict__ W,
                                                   float* __restrict__ h) {
    int row = blockIdx.x * blockDim.x + threadIdx.x;
    if (row >= NN) return;

    float xr[D];
    const float4* xp = reinterpret_cast<const float4*>(x + (size_t)row * D);
#pragma unroll
    for (int i = 0; i < D / 4; ++i) {
        float4 v = xp[i];
        xr[4 * i + 0] = v.x;
        xr[4 * i + 1] = v.y;
        xr[4 * i + 2] = v.z;
        xr[4 * i + 3] = v.w;
    }

    float* hrow = h + (size_t)row * D;
    for (int og = 0; og < D / 4; ++og) {
        const float* w0 = W + (size_t)(og * 4 + 0) * D;
        const float* w1 = W + (size_t)(og * 4 + 1) * D;
        const float* w2 = W + (size_t)(og * 4 + 2) * D;
        const float* w3 = W + (size_t)(og * 4 + 3) * D;
        float a0 = 0.f, a1 = 0.f, a2 = 0.f, a3 = 0.f;
#pragma unroll
        for (int k = 0; k < D; ++k) {
            float xv = xr[k];
            a0 = fmaf(xv, w0[k], a0);
            a1 = fmaf(xv, w1[k], a1);
            a2 = fmaf(xv, w2[k], a2);
            a3 = fmaf(xv, w3[k], a3);
        }
        float4 o;
        o.x = a0; o.y = a1; o.z = a2; o.w = a3;
        *reinterpret_cast<float4*>(hrow + og * 4) = o;
    }
}

// ---------------------------------------------------------------------------
// Scatter: out[dst[e]] += vals[e] * h[src[e]]  via HW fp32 atomics.
// One wave per edge; lane l owns dims [2l, 2l+1] (float2 -> coalesced 512B
// row gather). Grid-stride over edges.
// ---------------------------------------------------------------------------
__global__ __launch_bounds__(256) void scatter_kernel(const float* __restrict__ h,
                                                      const float* __restrict__ vals,
                                                      const int* __restrict__ src,
                                                      const int* __restrict__ dst,
                                                      float* __restrict__ out) {
    int lane = threadIdx.x & 63;
    int wid  = (int)((blockIdx.x * blockDim.x + threadIdx.x) >> 6);
    int nw   = (int)((gridDim.x * blockDim.x) >> 6);

    for (int e = wid; e < NE; e += nw) {
        int   s = src[e];
        int   d = dst[e];
        float v = vals[e];
        float2 hv = *reinterpret_cast<const float2*>(h + (size_t)s * D + lane * 2);
        float* op = out + (size_t)d * D + lane * 2;
        unsafeAtomicAdd(op + 0, v * hv.x);
        unsafeAtomicAdd(op + 1, v * hv.y);
    }
}

// ---------------------------------------------------------------------------
// Exact GELU in-place: out = 0.5*a*(1+erf(a/sqrt(2)))
// ---------------------------------------------------------------------------
__global__ __launch_bounds__(256) void gelu_kernel(float* __restrict__ out) {
    const int n4 = (NN * D) / 4;
    float4* p = reinterpret_cast<float4*>(out);
    int stride = gridDim.x * blockDim.x;
    for (int i = blockIdx.x * blockDim.x + threadIdx.x; i < n4; i += stride) {
        float4 v = p[i];
        v.x = 0.5f * v.x * (1.f + erff(v.x * 0.70710678118654752f));
        v.y = 0.5f * v.y * (1.f + erff(v.y * 0.70710678118654752f));
        v.z = 0.5f * v.z * (1.f + erff(v.z * 0.70710678118654752f));
        v.w = 0.5f * v.w * (1.f + erff(v.w * 0.70710678118654752f));
        p[i] = v;
    }
}

extern "C" void kernel_launch(void* const* d_in, const int* in_sizes, int n_in,
                              void* d_out, int out_size, void* d_ws, size_t ws_size,
                              hipStream_t stream) {
    const float* x    = (const float*)d_in[0];
    const float* W    = (const float*)d_in[1];
    const float* vals = (const float*)d_in[2];
    const int*   src  = (const int*)d_in[3];
    const int*   dst  = (const int*)d_in[4];
    float* out = (float*)d_out;
    float* h   = (float*)d_ws;   // 100000*128*4 = 51.2 MB scratch for h

    // Zero the accumulator (harness poisons d_out with 0xAA; atomics need 0).
    hipMemsetAsync(d_out, 0, (size_t)NN * D * sizeof(float), stream);

    gemm_kernel<<<(NN + 255) / 256, 256, 0, stream>>>(x, W, h);
    scatter_kernel<<<2048, 256, 0, stream>>>(h, vals, src, dst, out);
    gelu_kernel<<<2048, 256, 0, stream>>>(out);
}

// Round 2
// 654.441 us; speedup vs baseline: 2.5443x; 2.5443x over previous
//
#include <hip/hip_runtime.h>
#include <math.h>

#define NN 100000
#define NE 1600000
#define D 128
#define SCAN_BLOCKS ((NN + 255) / 256)   // 391

// ---------------------------------------------------------------------------
// GEMM: h[r][o] = sum_k x[r][k] * W[o][k]   (h = x @ W^T)  (unchanged)
// ---------------------------------------------------------------------------
__global__ __launch_bounds__(256) void gemm_kernel(const float* __restrict__ x,
                                                   const float* __restrict__ W,
                                                   float* __restrict__ h) {
    int row = blockIdx.x * blockDim.x + threadIdx.x;
    if (row >= NN) return;

    float xr[D];
    const float4* xp = reinterpret_cast<const float4*>(x + (size_t)row * D);
#pragma unroll
    for (int i = 0; i < D / 4; ++i) {
        float4 v = xp[i];
        xr[4 * i + 0] = v.x;
        xr[4 * i + 1] = v.y;
        xr[4 * i + 2] = v.z;
        xr[4 * i + 3] = v.w;
    }

    float* hrow = h + (size_t)row * D;
    for (int og = 0; og < D / 4; ++og) {
        const float* w0 = W + (size_t)(og * 4 + 0) * D;
        const float* w1 = W + (size_t)(og * 4 + 1) * D;
        const float* w2 = W + (size_t)(og * 4 + 2) * D;
        const float* w3 = W + (size_t)(og * 4 + 3) * D;
        float a0 = 0.f, a1 = 0.f, a2 = 0.f, a3 = 0.f;
#pragma unroll
        for (int k = 0; k < D; ++k) {
            float xv = xr[k];
            a0 = fmaf(xv, w0[k], a0);
            a1 = fmaf(xv, w1[k], a1);
            a2 = fmaf(xv, w2[k], a2);
            a3 = fmaf(xv, w3[k], a3);
        }
        float4 o;
        o.x = a0; o.y = a1; o.z = a2; o.w = a3;
        *reinterpret_cast<float4*>(hrow + og * 4) = o;
    }
}

// ---------------------------------------------------------------------------
// CSR build: histogram -> 3-kernel exclusive scan -> cursor fill
// ---------------------------------------------------------------------------
__global__ __launch_bounds__(256) void hist_kernel(const int* __restrict__ dst,
                                                   int* __restrict__ counts) {
    int stride = gridDim.x * blockDim.x;
    for (int e = blockIdx.x * blockDim.x + threadIdx.x; e < NE; e += stride)
        atomicAdd(&counts[dst[e]], 1);
}

// In-place exclusive scan of each 256-chunk; block totals to btot.
__global__ __launch_bounds__(256) void scan1_kernel(int* __restrict__ data,
                                                    int* __restrict__ btot) {
    __shared__ int lds[256];
    int tid = threadIdx.x;
    int gid = blockIdx.x * 256 + tid;
    int v = (gid < NN) ? data[gid] : 0;
    lds[tid] = v;
    __syncthreads();
    for (int off = 1; off < 256; off <<= 1) {
        int t = (tid >= off) ? lds[tid - off] : 0;
        __syncthreads();
        lds[tid] += t;
        __syncthreads();
    }
    int incl = lds[tid];
    if (gid < NN) data[gid] = incl - v;     // exclusive within block
    if (tid == 255) btot[blockIdx.x] = incl;
}

// Exclusive scan of the 391 block totals (single block of 512).
__global__ __launch_bounds__(512) void scan2_kernel(const int* __restrict__ btot,
                                                    int* __restrict__ boff) {
    __shared__ int lds[512];
    int tid = threadIdx.x;
    int v = (tid < SCAN_BLOCKS) ? btot[tid] : 0;
    lds[tid] = v;
    __syncthreads();
    for (int off = 1; off < 512; off <<= 1) {
        int t = (tid >= off) ? lds[tid - off] : 0;
        __syncthreads();
        lds[tid] += t;
        __syncthreads();
    }
    boff[tid] = lds[tid] - v;               // exclusive
}

// Add block offsets -> row_ptr; copy into cursor; set row_ptr[NN]=NE.
__global__ __launch_bounds__(256) void scan3_kernel(int* __restrict__ row_ptr,
                                                    const int* __restrict__ boff,
                                                    int* __restrict__ cursor) {
    int gid = blockIdx.x * 256 + threadIdx.x;
    if (gid < NN) {
        int r = row_ptr[gid] + boff[blockIdx.x];
        row_ptr[gid] = r;
        cursor[gid] = r;
    }
    if (gid == 0) row_ptr[NN] = NE;
}

__global__ __launch_bounds__(256) void fill_kernel(const int* __restrict__ src,
                                                   const int* __restrict__ dst,
                                                   const float* __restrict__ vals,
                                                   int* __restrict__ cursor,
                                                   int* __restrict__ csr_src,
                                                   float* __restrict__ csr_val) {
    int stride = gridDim.x * blockDim.x;
    for (int e = blockIdx.x * blockDim.x + threadIdx.x; e < NE; e += stride) {
        int d = dst[e];
        int p = atomicAdd(&cursor[d], 1);
        csr_src[p] = src[e];
        csr_val[p] = vals[e];
    }
}

// ---------------------------------------------------------------------------
// Pull aggregation + fused exact GELU.
// One wave per node; lane l owns dims [2l,2l+1]. 2-edge unroll for ILP.
// ---------------------------------------------------------------------------
__global__ __launch_bounds__(256) void pull_kernel(const float* __restrict__ h,
                                                   const int* __restrict__ row_ptr,
                                                   const int* __restrict__ csr_src,
                                                   const float* __restrict__ csr_val,
                                                   float* __restrict__ out) {
    int lane = threadIdx.x & 63;
    int node = blockIdx.x * 4 + (threadIdx.x >> 6);
    if (node >= NN) return;

    int beg = row_ptr[node];
    int end = row_ptr[node + 1];

    float a0 = 0.f, a1 = 0.f;
    int e = beg;
    for (; e + 1 < end; e += 2) {
        int s0 = csr_src[e];
        int s1 = csr_src[e + 1];
        float v0 = csr_val[e];
        float v1 = csr_val[e + 1];
        float2 h0 = *reinterpret_cast<const float2*>(h + (size_t)s0 * D + lane * 2);
        float2 h1 = *reinterpret_cast<const float2*>(h + (size_t)s1 * D + lane * 2);
        a0 = fmaf(v0, h0.x, a0);
        a1 = fmaf(v0, h0.y, a1);
        a0 = fmaf(v1, h1.x, a0);
        a1 = fmaf(v1, h1.y, a1);
    }
    if (e < end) {
        int s0 = csr_src[e];
        float v0 = csr_val[e];
        float2 h0 = *reinterpret_cast<const float2*>(h + (size_t)s0 * D + lane * 2);
        a0 = fmaf(v0, h0.x, a0);
        a1 = fmaf(v0, h0.y, a1);
    }

    const float is2 = 0.70710678118654752f;
    a0 = 0.5f * a0 * (1.f + erff(a0 * is2));
    a1 = 0.5f * a1 * (1.f + erff(a1 * is2));

    float2 o; o.x = a0; o.y = a1;
    *reinterpret_cast<float2*>(out + (size_t)node * D + lane * 2) = o;
}

extern "C" void kernel_launch(void* const* d_in, const int* in_sizes, int n_in,
                              void* d_out, int out_size, void* d_ws, size_t ws_size,
                              hipStream_t stream) {
    const float* x    = (const float*)d_in[0];
    const float* W    = (const float*)d_in[1];
    const float* vals = (const float*)d_in[2];
    const int*   src  = (const int*)d_in[3];
    const int*   dst  = (const int*)d_in[4];
    float* out = (float*)d_out;

    // Workspace layout (4-byte word offsets, each region 16B-aligned):
    //   h        : NN*D floats               (51.2 MB)
    //   row_ptr  : NN+1 ints  (also counts)  (400 KB)
    //   cursor   : NN ints                   (400 KB)
    //   csr_src  : NE ints                   (6.4 MB)
    //   csr_val  : NE floats                 (6.4 MB)
    //   btot/boff: SCAN_BLOCKS ints + 512 ints
    char* ws = (char*)d_ws;
    size_t off = 0;
    float* h        = (float*)(ws + off); off += (size_t)NN * D * 4;
    int*   row_ptr  = (int*)(ws + off);   off += ((size_t)NN + 4) * 4;
    int*   cursor   = (int*)(ws + off);   off += ((size_t)NN + 4) * 4;
    int*   csr_src  = (int*)(ws + off);   off += (size_t)NE * 4;
    float* csr_val  = (float*)(ws + off); off += (size_t)NE * 4;
    int*   btot     = (int*)(ws + off);   off += ((size_t)SCAN_BLOCKS + 1) * 4;
    int*   boff     = (int*)(ws + off);   off += 512 * 4;

    // counts := 0 (row_ptr buffer doubles as counts)
    hipMemsetAsync(row_ptr, 0, ((size_t)NN + 4) * 4, stream);

    gemm_kernel<<<(NN + 255) / 256, 256, 0, stream>>>(x, W, h);

    hist_kernel<<<1024, 256, 0, stream>>>(dst, row_ptr);
    scan1_kernel<<<SCAN_BLOCKS, 256, 0, stream>>>(row_ptr, btot);
    scan2_kernel<<<1, 512, 0, stream>>>(btot, boff);
    scan3_kernel<<<SCAN_BLOCKS, 256, 0, stream>>>(row_ptr, boff, cursor);
    fill_kernel<<<2048, 256, 0, stream>>>(src, dst, vals, cursor, csr_src, csr_val);

    pull_kernel<<<(NN + 3) / 4, 256, 0, stream>>>(h, row_ptr, csr_src, csr_val, out);
}

// Round 3
// 304.606 us; speedup vs baseline: 5.4664x; 2.1485x over previous
//
#include <hip/hip_runtime.h>
#include <math.h>

#define NN 100000
#define NE 1600000
#define D 128
#define SCAN_BLOCKS ((NN + 255) / 256)   // 391

#define BM 64            // rows per block in MFMA GEMM
#define LDT 136          // padded LDS row stride (bf16 units): 272 B, 16B-aligned

typedef __attribute__((ext_vector_type(8))) short bf16x8;
typedef __attribute__((ext_vector_type(4))) float f32x4;

__device__ __forceinline__ unsigned short f2bf(float f) {
    unsigned int u = __builtin_bit_cast(unsigned int, f);
    unsigned int r = (u + 0x7FFFu + ((u >> 16) & 1u)) >> 16;   // RTNE
    return (unsigned short)r;
}

// ---------------------------------------------------------------------------
// MFMA GEMM: h[r][o] = sum_k x[r][k] * W[o][k], bf16 inputs (converted in
// staging), fp32 accumulate, bf16 h output.
// Block: 256 threads (4 waves), BM=64 rows x 128 cols, K=128 (no K-loop).
// Wave w computes rows [w*16, w*16+16) x all 128 cols: M_rep=1, N_rep=8,
// 4 k-chunks of 32 -> 32 MFMAs/wave.
// ---------------------------------------------------------------------------
__global__ __launch_bounds__(256) void mfma_gemm_kernel(const float* __restrict__ x,
                                                        const float* __restrict__ W,
                                                        unsigned short* __restrict__ h) {
    __shared__ __align__(16) unsigned short lA[BM * LDT];    // 17408 B
    __shared__ __align__(16) unsigned short lB[128 * LDT];   // 34816 B
    const int tid = threadIdx.x;
    const int rowBase = blockIdx.x * BM;

    // Stage W (128x128 fp32 -> bf16): 4096 float4s, 16 per thread.
#pragma unroll
    for (int i = 0; i < 16; ++i) {
        int f = tid + 256 * i;
        int r = f >> 5, c4 = f & 31;
        float4 v = *reinterpret_cast<const float4*>(W + (size_t)r * D + c4 * 4);
        ushort4 b;
        b.x = f2bf(v.x); b.y = f2bf(v.y); b.z = f2bf(v.z); b.w = f2bf(v.w);
        *reinterpret_cast<ushort4*>(&lB[r * LDT + c4 * 4]) = b;
    }
    // Stage x tile (64x128 fp32 -> bf16): 2048 float4s, 8 per thread.
#pragma unroll
    for (int i = 0; i < 8; ++i) {
        int f = tid + 256 * i;
        int r = f >> 5, c4 = f & 31;
        int gr = rowBase + r;
        float4 v = {0.f, 0.f, 0.f, 0.f};
        if (gr < NN) v = *reinterpret_cast<const float4*>(x + (size_t)gr * D + c4 * 4);
        ushort4 b;
        b.x = f2bf(v.x); b.y = f2bf(v.y); b.z = f2bf(v.z); b.w = f2bf(v.w);
        *reinterpret_cast<ushort4*>(&lA[r * LDT + c4 * 4]) = b;
    }
    __syncthreads();

    const int lane = tid & 63;
    const int w = tid >> 6;
    const int l16 = lane & 15;
    const int koff = (lane >> 4) * 8;

    f32x4 acc[8];
#pragma unroll
    for (int j = 0; j < 8; ++j) acc[j] = (f32x4){0.f, 0.f, 0.f, 0.f};

    const int arow = w * 16 + l16;
#pragma unroll
    for (int kk = 0; kk < 4; ++kk) {
        int kbase = kk * 32 + koff;
        bf16x8 a = *reinterpret_cast<const bf16x8*>(&lA[arow * LDT + kbase]);
#pragma unroll
        for (int j = 0; j < 8; ++j) {
            bf16x8 b = *reinterpret_cast<const bf16x8*>(&lB[(j * 16 + l16) * LDT + kbase]);
            acc[j] = __builtin_amdgcn_mfma_f32_16x16x32_bf16(a, b, acc[j], 0, 0, 0);
        }
    }

    // C-write: D layout col=lane&15, row=(lane>>4)*4+q  [m89]
    const int crow0 = rowBase + w * 16 + (lane >> 4) * 4;
#pragma unroll
    for (int j = 0; j < 8; ++j) {
        int col = j * 16 + l16;
#pragma unroll
        for (int q = 0; q < 4; ++q) {
            int gr = crow0 + q;
            if (gr < NN) h[(size_t)gr * D + col] = f2bf(acc[j][q]);
        }
    }
}

// ---------------------------------------------------------------------------
// CSR build: histogram -> 3-kernel exclusive scan -> cursor fill
// ---------------------------------------------------------------------------
__global__ __launch_bounds__(256) void hist_kernel(const int* __restrict__ dst,
                                                   int* __restrict__ counts) {
    int stride = gridDim.x * blockDim.x;
    for (int e = blockIdx.x * blockDim.x + threadIdx.x; e < NE; e += stride)
        atomicAdd(&counts[dst[e]], 1);
}

__global__ __launch_bounds__(256) void scan1_kernel(int* __restrict__ data,
                                                    int* __restrict__ btot) {
    __shared__ int lds[256];
    int tid = threadIdx.x;
    int gid = blockIdx.x * 256 + tid;
    int v = (gid < NN) ? data[gid] : 0;
    lds[tid] = v;
    __syncthreads();
    for (int off = 1; off < 256; off <<= 1) {
        int t = (tid >= off) ? lds[tid - off] : 0;
        __syncthreads();
        lds[tid] += t;
        __syncthreads();
    }
    int incl = lds[tid];
    if (gid < NN) data[gid] = incl - v;
    if (tid == 255) btot[blockIdx.x] = incl;
}

__global__ __launch_bounds__(512) void scan2_kernel(const int* __restrict__ btot,
                                                    int* __restrict__ boff) {
    __shared__ int lds[512];
    int tid = threadIdx.x;
    int v = (tid < SCAN_BLOCKS) ? btot[tid] : 0;
    lds[tid] = v;
    __syncthreads();
    for (int off = 1; off < 512; off <<= 1) {
        int t = (tid >= off) ? lds[tid - off] : 0;
        __syncthreads();
        lds[tid] += t;
        __syncthreads();
    }
    boff[tid] = lds[tid] - v;
}

__global__ __launch_bounds__(256) void scan3_kernel(int* __restrict__ row_ptr,
                                                    const int* __restrict__ boff,
                                                    int* __restrict__ cursor) {
    int gid = blockIdx.x * 256 + threadIdx.x;
    if (gid < NN) {
        int r = row_ptr[gid] + boff[blockIdx.x];
        row_ptr[gid] = r;
        cursor[gid] = r;
    }
    if (gid == 0) row_ptr[NN] = NE;
}

__global__ __launch_bounds__(256) void fill_kernel(const int* __restrict__ src,
                                                   const int* __restrict__ dst,
                                                   const float* __restrict__ vals,
                                                   int* __restrict__ cursor,
                                                   int* __restrict__ csr_src,
                                                   float* __restrict__ csr_val) {
    int stride = gridDim.x * blockDim.x;
    for (int e = blockIdx.x * blockDim.x + threadIdx.x; e < NE; e += stride) {
        int d = dst[e];
        int p = atomicAdd(&cursor[d], 1);
        csr_src[p] = src[e];
        csr_val[p] = vals[e];
    }
}

// ---------------------------------------------------------------------------
// Pull aggregation + fused exact GELU. h is bf16: lane l owns dims [2l,2l+1],
// loads one uint (2 bf16) per edge -> 256 B/row coalesced gather, L2-resident.
// ---------------------------------------------------------------------------
__global__ __launch_bounds__(256) void pull_kernel(const unsigned short* __restrict__ h,
                                                   const int* __restrict__ row_ptr,
                                                   const int* __restrict__ csr_src,
                                                   const float* __restrict__ csr_val,
                                                   float* __restrict__ out) {
    int lane = threadIdx.x & 63;
    int node = blockIdx.x * 4 + (threadIdx.x >> 6);
    if (node >= NN) return;

    int beg = row_ptr[node];
    int end = row_ptr[node + 1];

    float a0 = 0.f, a1 = 0.f;
    int e = beg;
    for (; e + 1 < end; e += 2) {
        int s0 = csr_src[e];
        int s1 = csr_src[e + 1];
        float v0 = csr_val[e];
        float v1 = csr_val[e + 1];
        unsigned int u0 = *reinterpret_cast<const unsigned int*>(h + (size_t)s0 * D + lane * 2);
        unsigned int u1 = *reinterpret_cast<const unsigned int*>(h + (size_t)s1 * D + lane * 2);
        float h00 = __builtin_bit_cast(float, u0 << 16);
        float h01 = __builtin_bit_cast(float, u0 & 0xFFFF0000u);
        float h10 = __builtin_bit_cast(float, u1 << 16);
        float h11 = __builtin_bit_cast(float, u1 & 0xFFFF0000u);
        a0 = fmaf(v0, h00, a0);
        a1 = fmaf(v0, h01, a1);
        a0 = fmaf(v1, h10, a0);
        a1 = fmaf(v1, h11, a1);
    }
    if (e < end) {
        int s0 = csr_src[e];
        float v0 = csr_val[e];
        unsigned int u0 = *reinterpret_cast<const unsigned int*>(h + (size_t)s0 * D + lane * 2);
        a0 = fmaf(v0, __builtin_bit_cast(float, u0 << 16), a0);
        a1 = fmaf(v0, __builtin_bit_cast(float, u0 & 0xFFFF0000u), a1);
    }

    const float is2 = 0.70710678118654752f;
    a0 = 0.5f * a0 * (1.f + erff(a0 * is2));
    a1 = 0.5f * a1 * (1.f + erff(a1 * is2));

    float2 o; o.x = a0; o.y = a1;
    *reinterpret_cast<float2*>(out + (size_t)node * D + lane * 2) = o;
}

extern "C" void kernel_launch(void* const* d_in, const int* in_sizes, int n_in,
                              void* d_out, int out_size, void* d_ws, size_t ws_size,
                              hipStream_t stream) {
    const float* x    = (const float*)d_in[0];
    const float* W    = (const float*)d_in[1];
    const float* vals = (const float*)d_in[2];
    const int*   src  = (const int*)d_in[3];
    const int*   dst  = (const int*)d_in[4];
    float* out = (float*)d_out;

    // Workspace layout:
    //   h        : NN*D bf16                 (25.6 MB)
    //   row_ptr  : NN+1 ints  (also counts)  (400 KB)
    //   cursor   : NN ints                   (400 KB)
    //   csr_src  : NE ints                   (6.4 MB)
    //   csr_val  : NE floats                 (6.4 MB)
    //   btot/boff
    char* ws = (char*)d_ws;
    size_t off = 0;
    unsigned short* h = (unsigned short*)(ws + off); off += (size_t)NN * D * 2;
    int*   row_ptr  = (int*)(ws + off);   off += ((size_t)NN + 4) * 4;
    int*   cursor   = (int*)(ws + off);   off += ((size_t)NN + 4) * 4;
    int*   csr_src  = (int*)(ws + off);   off += (size_t)NE * 4;
    float* csr_val  = (float*)(ws + off); off += (size_t)NE * 4;
    int*   btot     = (int*)(ws + off);   off += ((size_t)SCAN_BLOCKS + 1) * 4;
    int*   boff     = (int*)(ws + off);   off += 512 * 4;

    hipMemsetAsync(row_ptr, 0, ((size_t)NN + 4) * 4, stream);

    mfma_gemm_kernel<<<(NN + BM - 1) / BM, 256, 0, stream>>>(x, W, h);

    hist_kernel<<<1024, 256, 0, stream>>>(dst, row_ptr);
    scan1_kernel<<<SCAN_BLOCKS, 256, 0, stream>>>(row_ptr, btot);
    scan2_kernel<<<1, 512, 0, stream>>>(btot, boff);
    scan3_kernel<<<SCAN_BLOCKS, 256, 0, stream>>>(row_ptr, boff, cursor);
    fill_kernel<<<2048, 256, 0, stream>>>(src, dst, vals, cursor, csr_src, csr_val);

    pull_kernel<<<(NN + 3) / 4, 256, 0, stream>>>(h, row_ptr, csr_src, csr_val, out);
}